// Round 2
// baseline (340.170 us; speedup 1.0000x reference)
//
#include <hip/hip_runtime.h>

// B = 1048576 rows, D = 64. xc = [x, sin(x)] (width 128).
// out[row] = { xc . w_sum + b,  exp2( log2|xc| . w_prod ) }
//
// R6 (resubmit; R1 bench was an infra failure "container failed twice"):
// 16 lanes per row (was 8). Lane q = tid&15 owns x-cols [4q..4q+3]:
//   - the float4 load address IS the linear global thread index (x4[g]) ->
//     perfectly coalesced, no address arithmetic;
//   - weights drop from 8 float4 (32 VGPR) to 4 float4 (16 VGPR) per lane;
//   - peak live VGPRs ~50 -> __launch_bounds__(256,8) forces <=64 VGPR,
//     8 waves/SIMD (full occupancy), no spill. The old 8-lane/ITER=8 version
//     held ~120+ live VGPRs under a 128 cap (spill/sink territory) at only
//     4 waves/SIMD -> kernel ran ~160us vs its ~44us HBM floor.
// Extra shuffle-reduce level (off=8) costs ~26% more reduce VALU per element;
// VALU has >2x headroom over the memory floor, so this is free.

typedef float vf4 __attribute__((ext_vector_type(4)));
typedef float vf2 __attribute__((ext_vector_type(2)));

#define BLOCK 256
#define ITER 4
#define INV_2PI 0.15915494309189535f

__global__ __launch_bounds__(BLOCK, 8) void fb_kernel(
    const vf4* __restrict__ x4,
    const vf4* __restrict__ wsum4,
    const float* __restrict__ b_sum,
    const vf4* __restrict__ wprod4,
    vf2*       __restrict__ out)
{
    const int tid = threadIdx.x;
    const int q   = tid & 15;

    // x-part weights (cols 4q..4q+3) and sin-part weights (cols 64+4q..64+4q+3)
    const vf4 wsX = wsum4[q];
    const vf4 wsS = wsum4[16 + q];
    const vf4 wpX = wprod4[q];
    const vf4 wpS = wprod4[16 + q];
    const float bias = b_sum[0];

    const int stride = gridDim.x * BLOCK;          // slice units (16 per row)
    const int g0     = blockIdx.x * BLOCK + tid;

    // ---- issue all ITER loads up front (nontemporal: stream-once) ----
    vf4 v[ITER];
#pragma unroll
    for (int it = 0; it < ITER; ++it)
        v[it] = __builtin_nontemporal_load(&x4[g0 + it * stride]);

    // ---- compute + 16-lane reduce + store per row-slice ----
#pragma unroll
    for (int it = 0; it < ITER; ++it) {
        const int g = g0 + it * stride;            // row = g >> 4
        float s = 0.f;   // sum-head partial
        float p = 0.f;   // product-head partial (base-2 log domain)

#pragma unroll
        for (int j = 0; j < 4; ++j) {
            const float xx = v[it][j];
            // |x| ~ N(0,1): x*INV_2PI stays deep inside v_sin_f32's domain,
            // skip the v_fract range reduction.
            const float sx = __builtin_amdgcn_sinf(xx * INV_2PI);
            s = fmaf(xx, wsX[j], s);
            s = fmaf(sx, wsS[j], s);
            p = fmaf(__log2f(fabsf(xx)), wpX[j], p);   // fabs folds into v_log input mod
            p = fmaf(__log2f(fabsf(sx)), wpS[j], p);
        }

#pragma unroll
        for (int off = 8; off > 0; off >>= 1) {
            s += __shfl_xor(s, off);
            p += __shfl_xor(p, off);
        }

        if (q == 0) {
            // exp(sum ln) == exp2(sum log2); v_exp_f32 is native exp2
            vf2 r;
            r.x = s + bias;
            r.y = __builtin_amdgcn_exp2f(p);
            __builtin_nontemporal_store(r, &out[g >> 4]);
        }
    }
}

extern "C" void kernel_launch(void* const* d_in, const int* in_sizes, int n_in,
                              void* d_out, int out_size, void* d_ws, size_t ws_size,
                              hipStream_t stream)
{
    const vf4*  x4     = (const vf4*)d_in[0];
    const vf4*  wsum4  = (const vf4*)d_in[1];
    const float* b_sum = (const float*)d_in[2];
    const vf4*  wprod4 = (const vf4*)d_in[3];
    vf2*        out    = (vf2*)d_out;

    const long rows   = (long)in_sizes[0] / 64;              // 1,048,576
    const int  blocks = (int)(rows * 16 / (BLOCK * ITER));   // 16384 (exact)

    hipLaunchKernelGGL(fb_kernel, dim3(blocks), dim3(BLOCK), 0, stream,
                       x4, wsum4, b_sum, wprod4, out);
}